// Round 10
// baseline (139.787 us; speedup 1.0000x reference)
//
#include <hip/hip_runtime.h>
#include <hip/hip_bf16.h>

#define NDIM  4096
#define MROWS 8192
// folded feature space: 1 + 16 + 136 + 816 = 969 distinct multiset products, padded to 16*64
#define PREAL 969
#define KP    1024   // 16 * 64
#define NT    16
#define NWFOLD 1024  // wfold blocks: 16 x 64

typedef unsigned short u16;
typedef __attribute__((ext_vector_type(8))) __bf16 bf16x8;
typedef __attribute__((ext_vector_type(8))) u16 u16x8;
typedef __attribute__((ext_vector_type(4))) float f32x4;

__device__ __forceinline__ u16 bf16rne(float f) {
  unsigned int u = __builtin_bit_cast(unsigned int, f);
  u += 0x7fffu + ((u >> 16) & 1u);
  return (u16)(u >> 16);
}

// -------- compile-time multiset table: TBL.v[p] = (i<<10)|(j<<5)|k, idx 16 = "1"; -1 = pad --------
struct Tbl { int v[KP]; };
constexpr Tbl make_table() {
  Tbl t{};
  for (int p = 0; p < KP; ++p) t.v[p] = -1;
  int p = 0;
  t.v[p++] = (16 << 10) | (16 << 5) | 16;                      // constant term
  for (int i = 0; i < 16; ++i) t.v[p++] = (i << 10) | (16 << 5) | 16;
  for (int i = 0; i < 16; ++i)
    for (int j = i; j < 16; ++j) t.v[p++] = (i << 10) | (j << 5) | 16;
  for (int i = 0; i < 16; ++i)
    for (int j = i; j < 16; ++j)
      for (int k = j; k < 16; ++k) t.v[p++] = (i << 10) | (j << 5) | k;
  return t;
}
__device__ constexpr Tbl TBL = make_table();

// -------- merged prep: blocks [0,NWFOLD) fold W; blocks [NWFOLD, NWFOLD+MROWS) build features --------
__global__ void prep_kernel(const float* __restrict__ z, const float* __restrict__ W,
                            const float* __restrict__ bias,
                            u16* __restrict__ xb, u16* __restrict__ wfbt) {
  __shared__ float tile[64][65];   // wfold transpose staging (65: 2-way conflicts = free)
  __shared__ float zs[17];
  const int bx = blockIdx.x;
  const int tid = threadIdx.x;

  if (bx < NWFOLD) {
    // ---- wfold: wfbt[d][p] = bf16( sum_{t in perms(p)} W[t][d] + (p==0 ? b[d] : 0) ) ----
    const int p0 = (bx & 15) * 64;
    const int d0 = (bx >> 4) * 64;
    const int d4 = (tid & 15) * 4;   // float4 column offset
    const int rb = tid >> 4;         // 0..15
    const int dd = d0 + d4;
#pragma unroll
    for (int pp = 0; pp < 4; ++pp) {
      const int r = pp * 16 + rb;
      const int p = p0 + r;
      const int enc = TBL.v[p];
      f32x4 v = {0.f, 0.f, 0.f, 0.f};
      if (enc >= 0) {
        const int i = enc >> 10, j = (enc >> 5) & 31, k = enc & 31;
        if (k == 16) {
          if (j == 16) {
            if (i == 16) {
              v = *reinterpret_cast<const f32x4*>(W + dd);
              f32x4 bb = *reinterpret_cast<const f32x4*>(bias + dd);
              v.x += bb.x; v.y += bb.y; v.z += bb.z; v.w += bb.w;
            } else {
              v = *reinterpret_cast<const f32x4*>(W + (size_t)(1 + i) * NDIM + dd);
            }
          } else {  // degree 2, i<=j
            v = *reinterpret_cast<const f32x4*>(W + (size_t)(17 + i * 16 + j) * NDIM + dd);
            if (i != j) {
              f32x4 w2 = *reinterpret_cast<const f32x4*>(W + (size_t)(17 + j * 16 + i) * NDIM + dd);
              v.x += w2.x; v.y += w2.y; v.z += w2.z; v.w += w2.w;
            }
          }
        } else {    // degree 3, i<=j<=k
          int rows[6];
          int nr = 0;
          rows[nr++] = 273 + i * 256 + j * 16 + k;
          if (i == j && j == k) {
          } else if (i == j) {
            rows[nr++] = 273 + i * 256 + k * 16 + i;
            rows[nr++] = 273 + k * 256 + i * 16 + i;
          } else if (j == k) {
            rows[nr++] = 273 + j * 256 + i * 16 + j;
            rows[nr++] = 273 + j * 256 + j * 16 + i;
          } else {
            rows[nr++] = 273 + i * 256 + k * 16 + j;
            rows[nr++] = 273 + j * 256 + i * 16 + k;
            rows[nr++] = 273 + j * 256 + k * 16 + i;
            rows[nr++] = 273 + k * 256 + i * 16 + j;
            rows[nr++] = 273 + k * 256 + j * 16 + i;
          }
          v = *reinterpret_cast<const f32x4*>(W + (size_t)rows[0] * NDIM + dd);
          for (int s = 1; s < nr; ++s) {
            f32x4 w2 = *reinterpret_cast<const f32x4*>(W + (size_t)rows[s] * NDIM + dd);
            v.x += w2.x; v.y += w2.y; v.z += w2.z; v.w += w2.w;
          }
        }
      }
#pragma unroll
      for (int jj = 0; jj < 4; ++jj) tile[r][d4 + jj] = v[jj];
    }
    __syncthreads();
#pragma unroll
    for (int round = 0; round < 2; ++round) {
      const int v = round * 256 + tid;
      const int d = v >> 3;   // 0..63
      const int tg = v & 7;   // 0..7
      u16x8 pack;
#pragma unroll
      for (int e = 0; e < 8; ++e) pack[e] = bf16rne(tile[tg * 8 + e][d]);
      *reinterpret_cast<u16x8*>(wfbt + (size_t)(d0 + d) * KP + p0 + tg * 8) = pack;
    }
  } else {
    // ---- feat: xb[row][p] = bf16( z_i * z_j * z_k ) ----
    const int row = bx - NWFOLD;
    if (tid < 16) zs[tid] = z[row * 16 + tid];
    if (tid == 16) zs[16] = 1.0f;
    __syncthreads();
    u16* xrow = xb + (size_t)row * KP;
    for (int g = tid; g < KP / 8; g += 256) {
      u16x8 pack;
#pragma unroll
      for (int e = 0; e < 8; ++e) {
        const int enc = TBL.v[g * 8 + e];
        float v = 0.0f;
        if (enc >= 0) v = zs[enc >> 10] * (zs[(enc >> 5) & 31] * zs[enc & 31]);
        pack[e] = bf16rne(v);
      }
      *reinterpret_cast<u16x8*>(xrow + g * 8) = pack;
    }
  }
}

// ------- persistent 2-N-tile 256x256 GEMM (R9 fence chain), grid = 256 blocks, K=1024 -------
#define GLOAD(gp, lp)                                                                     \
  __builtin_amdgcn_global_load_lds((const __attribute__((address_space(1))) unsigned int*)(gp), \
                                   (__attribute__((address_space(3))) unsigned int*)(lp), 16, 0, 0)

__device__ __forceinline__ void bar() {
  asm volatile("" ::: "memory");
  __builtin_amdgcn_s_barrier();
  asm volatile("" ::: "memory");
}

#define VM4 asm volatile("s_waitcnt vmcnt(4)" ::: "memory")
#define VM2 asm volatile("s_waitcnt vmcnt(2)" ::: "memory")
#define VM0 asm volatile("s_waitcnt vmcnt(0)" ::: "memory")

__global__ __launch_bounds__(512, 2) void gemm_kernel(const u16* __restrict__ xb,
                                                      const u16* __restrict__ wbt,
                                                      float* __restrict__ out) {
  __shared__ u16 lds[2 * 32768];  // 128 KiB: per buffer A[256][64] + B[256][64]

  // XCD swizzle: 256 blocks, per XCD 4 M-tiles x 8 N-pairs (each block does 2 N-tiles)
  const int bid  = blockIdx.x;
  const int xcd  = bid & 7;
  const int idx  = bid >> 3;            // 0..31 within XCD
  const int mtl  = idx >> 3;            // 0..3
  const int npr  = idx & 7;             // 0..7 N-pair
  const int brow = (xcd * 4 + mtl) * 256;
  const int bcol = npr * 512;

  const int tid  = threadIdx.x;
  const int lane = tid & 63;
  const int wid  = tid >> 6;   // 0..7
  const int wr   = wid >> 2;   // 0..1
  const int wc   = wid & 3;    // 0..3
  const int f    = lane & 15;
  const int q    = lane >> 4;
  const int f7   = f & 7;

  // staging geometry (R9): quarters matched to phase read-sets
  const int lr = lane >> 3;                         // 0..7
  const int swzc = ((lane & 7) ^ lr) * 8;           // pre-swizzled source chunk (u16)
  const u16* gA  = xb  + (size_t)(brow + lr) * KP + swzc;
  const u16* gB  = wbt + (size_t)(bcol + lr) * KP + swzc;         // N-tile 0
  const u16* gB2 = gB + (size_t)256 * KP;                         // N-tile 1
  const int aB0 = (wid >> 2) * 128 + (wid & 3) * 16;  // Ah0 base; Ah1 = +64
  const int bB0 = (wid >> 1) * 64 + (wid & 1) * 16;   // Bh0 base; Bh1 = +32

#define STGQ(gptr, region, rb, U) do {                                               \
    GLOAD((gptr) + (size_t)(rb) * KP + (U) * 64, (region) + (rb) * 64);              \
    GLOAD((gptr) + (size_t)((rb) + 8) * KP + (U) * 64, (region) + ((rb) + 8) * 64);  \
  } while (0)

#define RD_A(mi, kk) (*reinterpret_cast<const bf16x8*>(bufA + (wr * 128 + (mi) * 16 + f) * 64 + (((kk) * 4 + q) ^ f7) * 8))
#define RD_B(ni, kk) (*reinterpret_cast<const bf16x8*>(bufB + (wc * 64 + (ni) * 16 + f) * 64 + (((kk) * 4 + q) ^ f7) * 8))

#define RDA4(MOFF) do {                                                              \
    _Pragma("unroll") for (int _i = 0; _i < 4; ++_i) {                               \
      a_[_i][0] = RD_A((MOFF) + _i, 0); a_[_i][1] = RD_A((MOFF) + _i, 1); }          \
  } while (0)
#define RDB2(NOFF) do {                                                              \
    _Pragma("unroll") for (int _i = 0; _i < 2; ++_i) {                               \
      b_[(NOFF) + _i][0] = RD_B((NOFF) + _i, 0); b_[(NOFF) + _i][1] = RD_B((NOFF) + _i, 1); } \
  } while (0)

#define QUAD(MOFF, NOFF) do {                                                        \
    __builtin_amdgcn_s_setprio(1);                                                   \
    _Pragma("unroll") for (int _m = 0; _m < 4; ++_m)                                 \
    _Pragma("unroll") for (int _n = 0; _n < 2; ++_n)                                 \
    _Pragma("unroll") for (int _k = 0; _k < 2; ++_k)                                 \
      acc[(MOFF) + _m][(NOFF) + _n] = __builtin_amdgcn_mfma_f32_16x16x32_bf16(       \
          a_[_m][_k], b_[(NOFF) + _n][_k], acc[(MOFF) + _m][(NOFF) + _n], 0, 0, 0);  \
    __builtin_amdgcn_s_setprio(0);                                                   \
  } while (0)

// tile body: reads (cA,cB); stages K-tile U (A from gA, B from GBP) into (nA,nB)
#define TILE_BODY(cA, cB, nA, nB, U, GBP) do {                                       \
    bufA = (cA); bufB = (cB);                                                        \
    RDA4(0); RDB2(0); STGQ(gA, (nA), aB0, (U));                                      \
    bar(); QUAD(0, 0); VM4; bar();                                                   \
    RDB2(2);          STGQ((GBP), (nB), bB0, (U));                                   \
    bar(); QUAD(0, 2); VM4; bar();                                                   \
    RDA4(4);          STGQ((GBP), (nB), bB0 + 32, (U));                              \
    bar(); QUAD(4, 2); bar();                                                        \
                      STGQ(gA, (nA), aB0 + 64, (U));                                 \
    bar(); QUAD(4, 0); VM4; bar();                                                   \
  } while (0)

// final tile body (no staging): counted drains replace staging fences
#define TILE_LAST(cA, cB) do {                                                       \
    bufA = (cA); bufB = (cB);                                                        \
    RDA4(0); RDB2(0);                                                                \
    bar(); QUAD(0, 0); VM2; bar();                                                   \
    RDB2(2);                                                                         \
    bar(); QUAD(0, 2); VM0; bar();                                                   \
    RDA4(4);                                                                         \
    bar(); QUAD(4, 2); bar();                                                        \
    QUAD(4, 0);                                                                      \
  } while (0)

  f32x4 acc[8][4] = {};
  bf16x8 a_[4][2], b_[4][2];
  const u16 *bufA, *bufB;

  u16* b0A = lds;            u16* b0B = lds + 16384;
  u16* b1A = lds + 32768;    u16* b1B = b1A + 16384;

  // prologue: tile0 (pass 1) staged in read order
  STGQ(gA, b0A, aB0, 0); STGQ(gB, b0B, bB0, 0);
  STGQ(gB, b0B, bB0 + 32, 0); STGQ(gA, b0A, aB0 + 64, 0);
  VM4; bar();

  // ---------------- pass 1: N-tile at bcol ----------------
  for (int t = 0; t < NT - 2; t += 2) {
    TILE_BODY(b0A, b0B, b1A, b1B, t + 1, gB);
    TILE_BODY(b1A, b1B, b0A, b0B, t + 2, gB);
  }
  TILE_BODY(b0A, b0B, b1A, b1B, NT - 1, gB);   // t=14: reads buf0, stages k15 -> buf1
  TILE_BODY(b1A, b1B, b0A, b0B, 0, gB2);       // t=15: reads buf1, stages pass-2 k0 -> buf0

  // epilogue pass 1 (nontemporal; C never re-read). k0(pass2) loads hide under this.
  {
    const int r0 = brow + wr * 128 + q * 4;
    const int c0 = bcol + wc * 64 + f;
#pragma unroll
    for (int mi = 0; mi < 8; ++mi)
#pragma unroll
      for (int ni = 0; ni < 4; ++ni)
#pragma unroll
        for (int j = 0; j < 4; ++j)
          __builtin_nontemporal_store(acc[mi][ni][j],
              &out[(size_t)(r0 + mi * 16 + j) * NDIM + (c0 + ni * 16)]);
  }
  VM0; bar();   // pass-2 k0 resident block-wide; store queue drained

#pragma unroll
  for (int mi = 0; mi < 8; ++mi)
#pragma unroll
    for (int ni = 0; ni < 4; ++ni) {
      const f32x4 z4 = {0.f, 0.f, 0.f, 0.f};
      acc[mi][ni] = z4;
    }

  // ---------------- pass 2: N-tile at bcol + 256 ----------------
  for (int t = 0; t < NT - 2; t += 2) {
    TILE_BODY(b0A, b0B, b1A, b1B, t + 1, gB2);
    TILE_BODY(b1A, b1B, b0A, b0B, t + 2, gB2);
  }
  TILE_BODY(b0A, b0B, b1A, b1B, NT - 1, gB2);  // t=14: stages k15 -> buf1
  TILE_LAST(b1A, b1B);                          // t=15: reads buf1, no staging

  // epilogue pass 2
  {
    const int r0 = brow + wr * 128 + q * 4;
    const int c0 = bcol + 256 + wc * 64 + f;
#pragma unroll
    for (int mi = 0; mi < 8; ++mi)
#pragma unroll
      for (int ni = 0; ni < 4; ++ni)
#pragma unroll
        for (int j = 0; j < 4; ++j)
          __builtin_nontemporal_store(acc[mi][ni][j],
              &out[(size_t)(r0 + mi * 16 + j) * NDIM + (c0 + ni * 16)]);
  }
}

// ---------------- fallback (ws too small): correct fp32 path on raw features ----------------
__global__ void fallback_kernel(const float* __restrict__ z, const float* __restrict__ W,
                                const float* __restrict__ bias, float* __restrict__ out) {
  __shared__ float feat[4369];
  const int row = blockIdx.x;
  const int tid = threadIdx.x;
  for (int t = tid; t < 4369; t += 256) {
    float v;
    if (t == 0) v = 1.0f;
    else if (t < 17) v = z[row * 16 + t - 1];
    else if (t < 273) { int u = t - 17; v = z[row * 16 + (u >> 4)] * z[row * 16 + (u & 15)]; }
    else { int u = t - 273; v = z[row * 16 + ((u >> 8) & 15)] * (z[row * 16 + ((u >> 4) & 15)] * z[row * 16 + (u & 15)]); }
    feat[t] = v;
  }
  __syncthreads();
  float acc[16];
#pragma unroll
  for (int j = 0; j < 16; ++j) acc[j] = bias[tid + 256 * j];
  for (int t = 0; t < 4369; ++t) {
    const float fv = feat[t];
    const float* wrow = W + (size_t)t * NDIM;
#pragma unroll
    for (int j = 0; j < 16; ++j) acc[j] = fmaf(fv, wrow[tid + 256 * j], acc[j]);
  }
  float* orow = out + (size_t)row * NDIM;
#pragma unroll
  for (int j = 0; j < 16; ++j) orow[tid + 256 * j] = acc[j];
}

extern "C" void kernel_launch(void* const* d_in, const int* in_sizes, int n_in,
                              void* d_out, int out_size, void* d_ws, size_t ws_size,
                              hipStream_t stream) {
  const float* z = (const float*)d_in[0];
  const float* W = (const float*)d_in[1];
  const float* b = (const float*)d_in[2];
  float* out = (float*)d_out;

  const size_t xb_elems  = (size_t)MROWS * KP;
  const size_t wbt_elems = (size_t)NDIM * KP;
  const size_t need = (xb_elems + wbt_elems) * sizeof(u16);

  if (ws_size >= need) {
    u16* xb  = (u16*)d_ws;
    u16* wbt = xb + xb_elems;
    prep_kernel<<<NWFOLD + MROWS, 256, 0, stream>>>(z, W, b, xb, wbt);
    gemm_kernel<<<(MROWS / 256) * (NDIM / 512), 512, 0, stream>>>(xb, wbt, out);
  } else {
    fallback_kernel<<<MROWS, 256, 0, stream>>>(z, W, b, out);
  }
}

// Round 11
// 106.202 us; speedup vs baseline: 1.3162x; 1.3162x over previous
//
#include <hip/hip_runtime.h>
#include <hip/hip_bf16.h>

#define NDIM  4096
#define MROWS 8192
// folded feature space: 1 + 16 + 136 + 816 = 969 distinct multiset products, padded to 16*64
#define PREAL 969
#define KP    1024   // 16 * 64
#define NT    16
#define NWFOLD 1024  // wfold blocks: 16 x 64

typedef unsigned short u16;
typedef __attribute__((ext_vector_type(8))) __bf16 bf16x8;
typedef __attribute__((ext_vector_type(8))) u16 u16x8;
typedef __attribute__((ext_vector_type(4))) float f32x4;

__device__ __forceinline__ u16 bf16rne(float f) {
  unsigned int u = __builtin_bit_cast(unsigned int, f);
  u += 0x7fffu + ((u >> 16) & 1u);
  return (u16)(u >> 16);
}

// -------- compile-time multiset table: TBL.v[p] = (i<<10)|(j<<5)|k, idx 16 = "1"; -1 = pad --------
struct Tbl { int v[KP]; };
constexpr Tbl make_table() {
  Tbl t{};
  for (int p = 0; p < KP; ++p) t.v[p] = -1;
  int p = 0;
  t.v[p++] = (16 << 10) | (16 << 5) | 16;                      // constant term
  for (int i = 0; i < 16; ++i) t.v[p++] = (i << 10) | (16 << 5) | 16;
  for (int i = 0; i < 16; ++i)
    for (int j = i; j < 16; ++j) t.v[p++] = (i << 10) | (j << 5) | 16;
  for (int i = 0; i < 16; ++i)
    for (int j = i; j < 16; ++j)
      for (int k = j; k < 16; ++k) t.v[p++] = (i << 10) | (j << 5) | k;
  return t;
}
__device__ constexpr Tbl TBL = make_table();

// -------- merged prep: blocks [0,NWFOLD) fold W; blocks [NWFOLD, NWFOLD+MROWS) build features --------
__global__ void prep_kernel(const float* __restrict__ z, const float* __restrict__ W,
                            const float* __restrict__ bias,
                            u16* __restrict__ xb, u16* __restrict__ wfbt) {
  __shared__ float tile[64][65];   // wfold transpose staging (65: 2-way conflicts = free)
  __shared__ float zs[17];
  const int bx = blockIdx.x;
  const int tid = threadIdx.x;

  if (bx < NWFOLD) {
    // ---- wfold: wfbt[d][p] = bf16( sum_{t in perms(p)} W[t][d] + (p==0 ? b[d] : 0) ) ----
    const int p0 = (bx & 15) * 64;
    const int d0 = (bx >> 4) * 64;
    const int d4 = (tid & 15) * 4;   // float4 column offset
    const int rb = tid >> 4;         // 0..15
    const int dd = d0 + d4;
#pragma unroll
    for (int pp = 0; pp < 4; ++pp) {
      const int r = pp * 16 + rb;
      const int p = p0 + r;
      const int enc = TBL.v[p];
      f32x4 v = {0.f, 0.f, 0.f, 0.f};
      if (enc >= 0) {
        const int i = enc >> 10, j = (enc >> 5) & 31, k = enc & 31;
        if (k == 16) {
          if (j == 16) {
            if (i == 16) {
              v = *reinterpret_cast<const f32x4*>(W + dd);
              f32x4 bb = *reinterpret_cast<const f32x4*>(bias + dd);
              v.x += bb.x; v.y += bb.y; v.z += bb.z; v.w += bb.w;
            } else {
              v = *reinterpret_cast<const f32x4*>(W + (size_t)(1 + i) * NDIM + dd);
            }
          } else {  // degree 2, i<=j
            v = *reinterpret_cast<const f32x4*>(W + (size_t)(17 + i * 16 + j) * NDIM + dd);
            if (i != j) {
              f32x4 w2 = *reinterpret_cast<const f32x4*>(W + (size_t)(17 + j * 16 + i) * NDIM + dd);
              v.x += w2.x; v.y += w2.y; v.z += w2.z; v.w += w2.w;
            }
          }
        } else {    // degree 3, i<=j<=k
          int rows[6];
          int nr = 0;
          rows[nr++] = 273 + i * 256 + j * 16 + k;
          if (i == j && j == k) {
          } else if (i == j) {
            rows[nr++] = 273 + i * 256 + k * 16 + i;
            rows[nr++] = 273 + k * 256 + i * 16 + i;
          } else if (j == k) {
            rows[nr++] = 273 + j * 256 + i * 16 + j;
            rows[nr++] = 273 + j * 256 + j * 16 + i;
          } else {
            rows[nr++] = 273 + i * 256 + k * 16 + j;
            rows[nr++] = 273 + j * 256 + i * 16 + k;
            rows[nr++] = 273 + j * 256 + k * 16 + i;
            rows[nr++] = 273 + k * 256 + i * 16 + j;
            rows[nr++] = 273 + k * 256 + j * 16 + i;
          }
          v = *reinterpret_cast<const f32x4*>(W + (size_t)rows[0] * NDIM + dd);
          for (int s = 1; s < nr; ++s) {
            f32x4 w2 = *reinterpret_cast<const f32x4*>(W + (size_t)rows[s] * NDIM + dd);
            v.x += w2.x; v.y += w2.y; v.z += w2.z; v.w += w2.w;
          }
        }
      }
#pragma unroll
      for (int jj = 0; jj < 4; ++jj) tile[r][d4 + jj] = v[jj];
    }
    __syncthreads();
#pragma unroll
    for (int round = 0; round < 2; ++round) {
      const int v = round * 256 + tid;
      const int d = v >> 3;   // 0..63
      const int tg = v & 7;   // 0..7
      u16x8 pack;
#pragma unroll
      for (int e = 0; e < 8; ++e) pack[e] = bf16rne(tile[tg * 8 + e][d]);
      *reinterpret_cast<u16x8*>(wfbt + (size_t)(d0 + d) * KP + p0 + tg * 8) = pack;
    }
  } else {
    // ---- feat: xb[row][p] = bf16( z_i * z_j * z_k ) ----
    const int row = bx - NWFOLD;
    if (tid < 16) zs[tid] = z[row * 16 + tid];
    if (tid == 16) zs[16] = 1.0f;
    __syncthreads();
    u16* xrow = xb + (size_t)row * KP;
    for (int g = tid; g < KP / 8; g += 256) {
      u16x8 pack;
#pragma unroll
      for (int e = 0; e < 8; ++e) {
        const int enc = TBL.v[g * 8 + e];
        float v = 0.0f;
        if (enc >= 0) v = zs[enc >> 10] * (zs[(enc >> 5) & 31] * zs[enc & 31]);
        pack[e] = bf16rne(v);
      }
      *reinterpret_cast<u16x8*>(xrow + g * 8) = pack;
    }
  }
}

// ------- 256x256 GEMM, R9 fence chain, mid-phase barriers REMOVED (RD||MFMA wave slip) -------
#define GLOAD(gp, lp)                                                                     \
  __builtin_amdgcn_global_load_lds((const __attribute__((address_space(1))) unsigned int*)(gp), \
                                   (__attribute__((address_space(3))) unsigned int*)(lp), 16, 0, 0)

__device__ __forceinline__ void bar() {
  asm volatile("" ::: "memory");
  __builtin_amdgcn_s_barrier();
  asm volatile("" ::: "memory");
}

#define VM4 asm volatile("s_waitcnt vmcnt(4)" ::: "memory")
#define VM2 asm volatile("s_waitcnt vmcnt(2)" ::: "memory")
#define VM0 asm volatile("s_waitcnt vmcnt(0)" ::: "memory")

__global__ __launch_bounds__(512, 2) void gemm_kernel(const u16* __restrict__ xb,
                                                      const u16* __restrict__ wbt,
                                                      float* __restrict__ out) {
  __shared__ u16 lds[2 * 32768];  // 128 KiB: per buffer A[256][64] + B[256][64]

  // XCD swizzle, chunked 4Mx8N per concurrent 32-block round (nwg=512, 512%8==0)
  const int bid  = blockIdx.x;
  const int xcd  = bid & 7;
  const int idx  = bid >> 3;            // 0..63 within XCD
  const int mtl  = (idx >> 3) & 3;      // 4 M-tiles per XCD
  const int ntl  = (idx & 7) | ((idx >> 5) << 3);  // 8 N-tiles per round, 2 rounds
  const int brow = (xcd * 4 + mtl) * 256;
  const int bcol = ntl * 256;

  const int tid  = threadIdx.x;
  const int lane = tid & 63;
  const int wid  = tid >> 6;   // 0..7
  const int wr   = wid >> 2;   // 0..1
  const int wc   = wid & 3;    // 0..3
  const int f    = lane & 15;
  const int q    = lane >> 4;
  const int f7   = f & 7;

  // staging geometry (R9): quarters matched to phase read-sets
  const int lr = lane >> 3;                         // 0..7
  const int swzc = ((lane & 7) ^ lr) * 8;           // pre-swizzled source chunk (u16)
  const u16* gA = xb  + (size_t)(brow + lr) * KP + swzc;
  const u16* gB = wbt + (size_t)(bcol + lr) * KP + swzc;
  const int aB0 = (wid >> 2) * 128 + (wid & 3) * 16;  // Ah0 base; Ah1 = +64
  const int bB0 = (wid >> 1) * 64 + (wid & 1) * 16;   // Bh0 base; Bh1 = +32

#define STGQ(gptr, region, rb, U) do {                                               \
    GLOAD((gptr) + (size_t)(rb) * KP + (U) * 64, (region) + (rb) * 64);              \
    GLOAD((gptr) + (size_t)((rb) + 8) * KP + (U) * 64, (region) + ((rb) + 8) * 64);  \
  } while (0)

#define RD_A(mi, kk) (*reinterpret_cast<const bf16x8*>(bufA + (wr * 128 + (mi) * 16 + f) * 64 + (((kk) * 4 + q) ^ f7) * 8))
#define RD_B(ni, kk) (*reinterpret_cast<const bf16x8*>(bufB + (wc * 64 + (ni) * 16 + f) * 64 + (((kk) * 4 + q) ^ f7) * 8))

#define RDA4(MOFF) do {                                                              \
    _Pragma("unroll") for (int _i = 0; _i < 4; ++_i) {                               \
      a_[_i][0] = RD_A((MOFF) + _i, 0); a_[_i][1] = RD_A((MOFF) + _i, 1); }          \
  } while (0)
#define RDB2(NOFF) do {                                                              \
    _Pragma("unroll") for (int _i = 0; _i < 2; ++_i) {                               \
      b_[(NOFF) + _i][0] = RD_B((NOFF) + _i, 0); b_[(NOFF) + _i][1] = RD_B((NOFF) + _i, 1); } \
  } while (0)

#define QUAD(MOFF, NOFF) do {                                                        \
    __builtin_amdgcn_s_setprio(1);                                                   \
    _Pragma("unroll") for (int _m = 0; _m < 4; ++_m)                                 \
    _Pragma("unroll") for (int _n = 0; _n < 2; ++_n)                                 \
    _Pragma("unroll") for (int _k = 0; _k < 2; ++_k)                                 \
      acc[(MOFF) + _m][(NOFF) + _n] = __builtin_amdgcn_mfma_f32_16x16x32_bf16(       \
          a_[_m][_k], b_[(NOFF) + _n][_k], acc[(MOFF) + _m][(NOFF) + _n], 0, 0, 0);  \
    __builtin_amdgcn_s_setprio(0);                                                   \
  } while (0)

// tile body, NO mid-phase barriers: per phase {RD; STG; QUAD; [fence]; bar}.
// Hazard audit: QUAD touches registers only; RD reads buf(t), STG writes buf(t+1) ->
// no intra-phase LDS hazard; all residency/swap hazards carried by the fences +
// END-of-phase barriers, unchanged from R9. Compiler emits lgkmcnt for RD->QUAD deps.
#define TILE_BODY(cA, cB, nA, nB, U) do {                                            \
    bufA = (cA); bufB = (cB);                                                        \
    RDA4(0); RDB2(0); STGQ(gA, (nA), aB0, (U));                                      \
    QUAD(0, 0); VM4; bar();                                                          \
    RDB2(2);          STGQ(gB, (nB), bB0, (U));                                      \
    QUAD(0, 2); VM4; bar();                                                          \
    RDA4(4);          STGQ(gB, (nB), bB0 + 32, (U));                                 \
    QUAD(4, 2); bar();                                                               \
                      STGQ(gA, (nA), aB0 + 64, (U));                                 \
    QUAD(4, 0); VM4; bar();                                                          \
  } while (0)

// final tile body (no staging): counted drains replace staging fences (R10-validated)
#define TILE_LAST(cA, cB) do {                                                       \
    bufA = (cA); bufB = (cB);                                                        \
    RDA4(0); RDB2(0);                                                                \
    QUAD(0, 0); VM2; bar();                                                          \
    RDB2(2);                                                                         \
    QUAD(0, 2); VM0; bar();                                                          \
    RDA4(4);                                                                         \
    QUAD(4, 2); bar();                                                               \
    QUAD(4, 0);                                                                      \
  } while (0)

  f32x4 acc[8][4] = {};
  bf16x8 a_[4][2], b_[4][2];
  const u16 *bufA, *bufB;

  u16* b0A = lds;            u16* b0B = lds + 16384;
  u16* b1A = lds + 32768;    u16* b1B = b1A + 16384;

  // prologue: stage tile0's 4 quarters in read order; vmcnt(4) -> Ah0,Bh0 resident
  STGQ(gA, b0A, aB0, 0); STGQ(gB, b0B, bB0, 0);
  STGQ(gB, b0B, bB0 + 32, 0); STGQ(gA, b0A, aB0 + 64, 0);
  VM4; bar();

  for (int t = 0; t < NT - 2; t += 2) {             // tiles 0..13
    TILE_BODY(b0A, b0B, b1A, b1B, t + 1);           // even tile: reads buf0, stages t+1
    TILE_BODY(b1A, b1B, b0A, b0B, t + 2);           // odd tile:  reads buf1, stages t+2
  }
  TILE_BODY(b0A, b0B, b1A, b1B, NT - 1);            // tile 14: stages tile 15 -> buf1
  TILE_LAST(b1A, b1B);                              // tile 15: no staging

  // epilogue: plain cached stores (R10 lesson: nontemporal 4B stores amplify writes)
  const int r0 = brow + wr * 128 + q * 4;
  const int c0 = bcol + wc * 64 + f;
#pragma unroll
  for (int mi = 0; mi < 8; ++mi)
#pragma unroll
    for (int ni = 0; ni < 4; ++ni) {
#pragma unroll
      for (int j = 0; j < 4; ++j)
        out[(size_t)(r0 + mi * 16 + j) * NDIM + (c0 + ni * 16)] = acc[mi][ni][j];
    }
}

// ---------------- fallback (ws too small): correct fp32 path on raw features ----------------
__global__ void fallback_kernel(const float* __restrict__ z, const float* __restrict__ W,
                                const float* __restrict__ bias, float* __restrict__ out) {
  __shared__ float feat[4369];
  const int row = blockIdx.x;
  const int tid = threadIdx.x;
  for (int t = tid; t < 4369; t += 256) {
    float v;
    if (t == 0) v = 1.0f;
    else if (t < 17) v = z[row * 16 + t - 1];
    else if (t < 273) { int u = t - 17; v = z[row * 16 + (u >> 4)] * z[row * 16 + (u & 15)]; }
    else { int u = t - 273; v = z[row * 16 + ((u >> 8) & 15)] * (z[row * 16 + ((u >> 4) & 15)] * z[row * 16 + (u & 15)]); }
    feat[t] = v;
  }
  __syncthreads();
  float acc[16];
#pragma unroll
  for (int j = 0; j < 16; ++j) acc[j] = bias[tid + 256 * j];
  for (int t = 0; t < 4369; ++t) {
    const float fv = feat[t];
    const float* wrow = W + (size_t)t * NDIM;
#pragma unroll
    for (int j = 0; j < 16; ++j) acc[j] = fmaf(fv, wrow[tid + 256 * j], acc[j]);
  }
  float* orow = out + (size_t)row * NDIM;
#pragma unroll
  for (int j = 0; j < 16; ++j) orow[tid + 256 * j] = acc[j];
}

extern "C" void kernel_launch(void* const* d_in, const int* in_sizes, int n_in,
                              void* d_out, int out_size, void* d_ws, size_t ws_size,
                              hipStream_t stream) {
  const float* z = (const float*)d_in[0];
  const float* W = (const float*)d_in[1];
  const float* b = (const float*)d_in[2];
  float* out = (float*)d_out;

  const size_t xb_elems  = (size_t)MROWS * KP;
  const size_t wbt_elems = (size_t)NDIM * KP;
  const size_t need = (xb_elems + wbt_elems) * sizeof(u16);

  if (ws_size >= need) {
    u16* xb  = (u16*)d_ws;
    u16* wbt = xb + xb_elems;
    prep_kernel<<<NWFOLD + MROWS, 256, 0, stream>>>(z, W, b, xb, wbt);
    gemm_kernel<<<(MROWS / 256) * (NDIM / 256), 512, 0, stream>>>(xb, wbt, out);
  } else {
    fallback_kernel<<<MROWS, 256, 0, stream>>>(z, W, b, out);
  }
}